// Round 1
// baseline (1764.124 us; speedup 1.0000x reference)
//
#include <hip/hip_runtime.h>

typedef _Float16 f16;
typedef _Float16 f16x8 __attribute__((ext_vector_type(8)));
typedef float    f32x4 __attribute__((ext_vector_type(4)));

// Problem constants (R=256, C=256, B=1, E=768, H=12, Dh=64)
// scaling = Dh^-0.5 / sqrt(R) = (1/8)/16 = 1/128
#define NTOK 65536
#define EDIM 768

// ws layout (bytes); CTX reuses Xh region (Xh dead after V projection)
#define OFF_XH   0UL          // 65536*768 f16 = 100663296 B   (also CTX)
#define OFF_QT   100663296UL  // head-major [h][i][r*64+d] f16
#define OFF_KT   201326592UL
#define OFF_VT   301989888UL  // transposed [e][n] f16
#define OFF_WQ   402653184UL  // 768*768 f16 = 1179648 B
#define OFF_WK   403832832UL
#define OFF_WV   405012480UL
#define OFF_WO   406192128UL
#define OFF_S    407371776UL  // 12*256*256 f32 = 3145728 B
#define OFF_PH   410517504UL  // 12*256*256 f16 = 1572864 B
// total 412090368 B (~393 MB)

__global__ __launch_bounds__(256) void cast_f32_f16(const float* __restrict__ in,
                                                    f16* __restrict__ out, int n8) {
    int i = blockIdx.x * 256 + threadIdx.x;
    if (i >= n8) return;
    const float4* p = (const float4*)in;
    float4 a = p[2*i], b = p[2*i+1];
    f16x8 o;
    o[0]=(f16)a.x; o[1]=(f16)a.y; o[2]=(f16)a.z; o[3]=(f16)a.w;
    o[4]=(f16)b.x; o[5]=(f16)b.y; o[6]=(f16)b.z; o[7]=(f16)b.w;
    ((f16x8*)out)[i] = o;
}

enum { MODE_QK = 0, MODE_V = 1, MODE_S = 2, MODE_CTX = 3, MODE_OUT = 4 };

// NT GEMM: C[m,n] = sum_k A[m,k]*B[n,k]; A/B fp16, fp32 accum.
// 256 threads = 4 waves in 2x2 grid; each wave computes (WMT*16)x(WNT*16).
template<int BM, int BN, int BK, int WMT, int WNT, int MODE>
__global__ __launch_bounds__(256) void gemm_nt(
    const f16* __restrict__ A0, const f16* __restrict__ B0,
    float* __restrict__ outF, f16* __restrict__ outH,
    const float* __restrict__ bias, float scale,
    int lda, int ldb, int K)
{
    static_assert(BK == 64, "staging assumes BK=64");
    __shared__ f16 As[BM*(BK+8)];
    __shared__ f16 Bs[BN*(BK+8)];
    const int tid = threadIdx.x;
    const int m0 = blockIdx.y * BM;
    const int n0 = blockIdx.x * BN;
    const int z  = blockIdx.z;

    const f16* A = A0;
    const f16* B = B0;
    if constexpr (MODE == MODE_S) {
        A += (long)z * 256 * 16384;          // Qt head z
        B += (long)z * 256 * 16384;          // Kt head z
    } else if constexpr (MODE == MODE_CTX) {
        const int h = z >> 8, r = z & 255;
        A += (long)h * 65536;                // Ph + h*256*256
        B += (long)h * 64 * 65536 + r * 256; // Vt[h*64 + d][r*256 + j]
    }

    const int wave = tid >> 6, lane = tid & 63;
    const int wm = wave >> 1, wn = wave & 1;
    const int lrow = lane & 15, quad = lane >> 4;

    f32x4 acc[WMT][WNT];
    #pragma unroll
    for (int i = 0; i < WMT; i++)
        #pragma unroll
        for (int j = 0; j < WNT; j++)
            acc[i][j] = (f32x4){0.f, 0.f, 0.f, 0.f};

    const int ASEGS = BM * BK / 8;
    const int BSEGS = BN * BK / 8;

    for (int k0 = 0; k0 < K; k0 += BK) {
        __syncthreads();
        #pragma unroll
        for (int s = tid; s < ASEGS; s += 256) {
            int row = s >> 3, seg = s & 7;   // BK/8 = 8 segs of 8 halfs
            *(f16x8*)&As[row*(BK+8) + seg*8] =
                *(const f16x8*)&A[(long)(m0+row)*lda + k0 + seg*8];
        }
        #pragma unroll
        for (int s = tid; s < BSEGS; s += 256) {
            int row = s >> 3, seg = s & 7;
            *(f16x8*)&Bs[row*(BK+8) + seg*8] =
                *(const f16x8*)&B[(long)(n0+row)*ldb + k0 + seg*8];
        }
        __syncthreads();
        #pragma unroll
        for (int kk = 0; kk < BK; kk += 32) {
            f16x8 af[WMT], bf[WNT];
            #pragma unroll
            for (int i = 0; i < WMT; i++)
                af[i] = *(const f16x8*)&As[(wm*WMT*16 + i*16 + lrow)*(BK+8) + kk + quad*8];
            #pragma unroll
            for (int j = 0; j < WNT; j++)
                bf[j] = *(const f16x8*)&Bs[(wn*WNT*16 + j*16 + lrow)*(BK+8) + kk + quad*8];
            #pragma unroll
            for (int i = 0; i < WMT; i++)
                #pragma unroll
                for (int j = 0; j < WNT; j++)
                    acc[i][j] = __builtin_amdgcn_mfma_f32_16x16x32_f16(af[i], bf[j], acc[i][j], 0, 0, 0);
        }
    }

    // Epilogue. D-layout: col = lane&15 (n), row = quad*4 + reg (m)
    #pragma unroll
    for (int i = 0; i < WMT; i++) {
        #pragma unroll
        for (int j = 0; j < WNT; j++) {
            #pragma unroll
            for (int r = 0; r < 4; r++) {
                int m = m0 + wm*WMT*16 + i*16 + quad*4 + r;
                int n = n0 + wn*WNT*16 + j*16 + lrow;
                float v = acc[i][j][r];
                if constexpr (MODE == MODE_QK) {
                    v = (v + bias[n]) * scale;
                    int hh = n >> 6, d = n & 63, rr = m >> 8, ii = m & 255;
                    outH[((long)((hh*256 + ii)*256 + rr) << 6) + d] = (f16)v;
                } else if constexpr (MODE == MODE_V) {
                    v = v + bias[n];
                    outH[(long)n * NTOK + m] = (f16)v;   // Vt[e][token]
                } else if constexpr (MODE == MODE_S) {
                    outF[(long)z * 65536 + m*256 + n] = v;
                } else if constexpr (MODE == MODE_CTX) {
                    int h = z >> 8, r_ = z & 255;
                    outH[((long)(r_*256 + m))*EDIM + h*64 + n] = (f16)v;
                } else { // MODE_OUT
                    outF[(long)m * EDIM + n] = v + bias[n];
                }
            }
        }
    }
}

__global__ __launch_bounds__(256) void softmax_k(const float* __restrict__ S,
                                                 float* __restrict__ pOut,
                                                 f16* __restrict__ Ph) {
    __shared__ float red[8];
    const int row = blockIdx.x;   // h*256 + i
    const int t = threadIdx.x;
    float v = S[(long)row*256 + t];
    float mx = v;
    #pragma unroll
    for (int o = 32; o; o >>= 1) mx = fmaxf(mx, __shfl_xor(mx, o, 64));
    if ((t & 63) == 0) red[t >> 6] = mx;
    __syncthreads();
    mx = fmaxf(fmaxf(red[0], red[1]), fmaxf(red[2], red[3]));
    float e = expf(v - mx);
    float s = e;
    #pragma unroll
    for (int o = 32; o; o >>= 1) s += __shfl_xor(s, o, 64);
    if ((t & 63) == 0) red[4 + (t >> 6)] = s;
    __syncthreads();
    s = red[4] + red[5] + red[6] + red[7];
    float p = e / s;
    pOut[(long)row*256 + t] = p;
    Ph[(long)row*256 + t] = (f16)p;
}

extern "C" void kernel_launch(void* const* d_in, const int* in_sizes, int n_in,
                              void* d_out, int out_size, void* d_ws, size_t ws_size,
                              hipStream_t stream) {
    const float* x  = (const float*)d_in[0];
    const float* Wq = (const float*)d_in[1];
    const float* bq = (const float*)d_in[2];
    const float* Wk = (const float*)d_in[3];
    const float* bk = (const float*)d_in[4];
    const float* Wv = (const float*)d_in[5];
    const float* bv = (const float*)d_in[6];
    const float* Wo = (const float*)d_in[7];
    const float* bo = (const float*)d_in[8];
    float* out   = (float*)d_out;
    float* probs = out + 50331648L;

    char* ws = (char*)d_ws;
    f16*  Xh   = (f16*)(ws + OFF_XH);
    f16*  CTXh = (f16*)(ws + OFF_XH);   // alias: Xh dead after V projection
    f16*  Qt   = (f16*)(ws + OFF_QT);
    f16*  Kt   = (f16*)(ws + OFF_KT);
    f16*  Vt   = (f16*)(ws + OFF_VT);
    f16*  Wqh  = (f16*)(ws + OFF_WQ);
    f16*  Wkh  = (f16*)(ws + OFF_WK);
    f16*  Wvh  = (f16*)(ws + OFF_WV);
    f16*  Woh  = (f16*)(ws + OFF_WO);
    float* Sws = (float*)(ws + OFF_S);
    f16*  Ph   = (f16*)(ws + OFF_PH);

    // casts: X (50,331,648 elems) and 4 weights (589,824 each)
    cast_f32_f16<<<24576, 256, 0, stream>>>(x,  Xh,  6291456);
    cast_f32_f16<<<288,   256, 0, stream>>>(Wq, Wqh, 73728);
    cast_f32_f16<<<288,   256, 0, stream>>>(Wk, Wkh, 73728);
    cast_f32_f16<<<288,   256, 0, stream>>>(Wv, Wvh, 73728);
    cast_f32_f16<<<288,   256, 0, stream>>>(Wo, Woh, 73728);

    // projections: M=65536, N=768, K=768
    dim3 g1(6, 512, 1);
    gemm_nt<128,128,64,4,4,MODE_QK><<<g1, 256, 0, stream>>>(Xh, Wqh, nullptr, Qt, bq, 1.0f/128.0f, 768, 768, 768);
    gemm_nt<128,128,64,4,4,MODE_QK><<<g1, 256, 0, stream>>>(Xh, Wkh, nullptr, Kt, bk, 1.0f,        768, 768, 768);
    gemm_nt<128,128,64,4,4,MODE_V ><<<g1, 256, 0, stream>>>(Xh, Wvh, nullptr, Vt, bv, 1.0f,        768, 768, 768);

    // scores: per head, M=N=256, K=16384
    gemm_nt<64,64,64,2,2,MODE_S><<<dim3(4,4,12), 256, 0, stream>>>(Qt, Kt, Sws, nullptr, nullptr, 1.0f, 16384, 16384, 16384);

    // softmax over rows (12*256 rows of 256)
    softmax_k<<<3072, 256, 0, stream>>>(Sws, probs, Ph);

    // context: per (h,r), M=256(i), N=64(d), K=256(j)
    gemm_nt<64,64,64,2,2,MODE_CTX><<<dim3(1,4,3072), 256, 0, stream>>>(Ph, Vt, nullptr, CTXh, nullptr, 1.0f, 256, 65536, 256);

    // output projection: M=65536, N=768, K=768, fp32 out + bias
    gemm_nt<128,128,64,4,4,MODE_OUT><<<g1, 256, 0, stream>>>(CTXh, Woh, out, nullptr, bo, 1.0f, 768, 768, 768);
}

// Round 2
// 988.233 us; speedup vs baseline: 1.7851x; 1.7851x over previous
//
#include <hip/hip_runtime.h>
#include <cstdint>

typedef _Float16 f16;
typedef _Float16 f16x8 __attribute__((ext_vector_type(8)));
typedef float    f32x4 __attribute__((ext_vector_type(4)));

// Problem: R=256, C=256, B=1, E=768, H=12, Dh=64. scaling = (1/8)/16 = 1/128.
// Tokens m = r*256 + i (x is (R,C,B,E) row-major).
//
// ws layout (bytes):
#define OFF_XH   0UL           // Xh 100 MB; DEAD after V-proj -> reused as Spart (50 MB) then CTXh (100 MB)
#define OFF_QT   100663296UL   // Qt  [h][i][r*64+d] f16, 100 MB
#define OFF_KT   201326592UL   // Kt  same layout
#define OFF_VT   301989888UL   // Vt2 [h][r][d][j]   f16, 100 MB
#define OFF_WQ   402653184UL
#define OFF_WK   403832832UL
#define OFF_WV   405012480UL
#define OFF_WO   406192128UL
#define OFF_PH   407371776UL   // probs f16 [h][i][j], 1.5 MB
// total ~409 MB (round-0's 412 MB fit, so ws_size is sufficient)

__global__ __launch_bounds__(256) void cast_f32_f16(const float* __restrict__ in,
                                                    f16* __restrict__ out, int n8) {
    int i = blockIdx.x * 256 + threadIdx.x;
    if (i >= n8) return;
    const float4* p = (const float4*)in;
    float4 a = p[2*i], b = p[2*i+1];
    f16x8 o;
    o[0]=(f16)a.x; o[1]=(f16)a.y; o[2]=(f16)a.z; o[3]=(f16)a.w;
    o[4]=(f16)b.x; o[5]=(f16)b.y; o[6]=(f16)b.z; o[7]=(f16)b.w;
    ((f16x8*)out)[i] = o;
}

enum { MODE_QK = 0, MODE_V = 1, MODE_SPLIT = 2, MODE_CTX = 3, MODE_OUT = 4 };

__device__ __forceinline__ void gl_lds16(const f16* g, f16* l) {
    auto gp = (const __attribute__((address_space(1))) f16*)(g);
    auto lp = (__attribute__((address_space(3))) f16*)(l);
    __builtin_amdgcn_global_load_lds(gp, lp, 16, 0, 0);
}

// m97-pattern NT GEMM: C[m,n] = sum_k A[m,k]*B[n,k]. BM=BN=128, BK=64,
// 256 thr = 4 waves (2x2), 4x4 MFMA tiles/wave, 16x16x32 f16 MFMA.
// Staging: global_load_lds width=16, unpadded LDS rows (64 halfs = 128 B).
// Bank conflicts avoided by XOR-swizzling the SOURCE column: LDS[row][s]
// holds global k-seg (s ^ (row&7)); fragment reads un-swizzle. 2-way max.
template<int MODE>
__global__ __launch_bounds__(256) void gemm_fast(
    const f16* __restrict__ A, const f16* __restrict__ B,
    float* __restrict__ outF, f16* __restrict__ outH,
    const float* __restrict__ bias, float scale,
    int lda, int ldb, int K)
{
    __shared__ f16 As[128*64];
    __shared__ f16 Bs[128*64];
    const int tid = threadIdx.x;
    const int wv = tid >> 6, ln = tid & 63;
    const int lrow = ln & 15, quad = ln >> 4;
    const int wm = wv >> 1, wn = wv & 1;
    const int m0 = blockIdx.y * 128;
    const int n0 = blockIdx.x * 128;
    const int z = blockIdx.z;
    int h = 0, sp = 0;
    if constexpr (MODE == MODE_SPLIT) {
        h = z >> 4; sp = z & 15;
        A += (long)h*4194304 + sp*1024;   // Qt head h, k-window [sp*1024, +1024)
        B += (long)h*4194304 + sp*1024;   // Kt head h
    } else if constexpr (MODE == MODE_CTX) {
        A += (long)z * 65536;             // Ph head z  (256x256 f16)
        B += (long)z * 4194304;           // Vt2 head z (16384x256 f16)
    }

    // staging geometry: chunk c = wv*4 + t covers rows [c*8, c*8+8)
    const int srow = wv*32 + (ln >> 3);               // + t*8 per round
    const int scol = ((ln & 7) ^ (srow & 7)) << 3;    // XOR swizzle (t*8 doesn't change row&7)
    const f16* ga = A + (long)(m0 + srow)*lda + scol;
    const f16* gb = B + (long)(n0 + srow)*ldb + scol;

    f32x4 acc[4][4] = {};

    for (int k0 = 0; k0 < K; k0 += 64) {
        __syncthreads();
        #pragma unroll
        for (int t = 0; t < 4; t++) {
            gl_lds16(ga + (long)t*8*lda, As + (wv*4 + t)*512);
            gl_lds16(gb + (long)t*8*ldb, Bs + (wv*4 + t)*512);
        }
        ga += 64; gb += 64;
        __syncthreads();   // drains vmcnt(0): LDS tiles ready
        #pragma unroll
        for (int ks = 0; ks < 2; ks++) {
            const int slot = ((ks*4 + quad) ^ (lrow & 7)) << 3;  // un-swizzle
            f16x8 af[4], bf[4];
            #pragma unroll
            for (int i = 0; i < 4; i++)
                af[i] = *(const f16x8*)&As[(wm*64 + i*16 + lrow)*64 + slot];
            #pragma unroll
            for (int j = 0; j < 4; j++)
                bf[j] = *(const f16x8*)&Bs[(wn*64 + j*16 + lrow)*64 + slot];
            #pragma unroll
            for (int i = 0; i < 4; i++)
                #pragma unroll
                for (int j = 0; j < 4; j++)
                    acc[i][j] = __builtin_amdgcn_mfma_f32_16x16x32_f16(af[i], bf[j], acc[i][j], 0, 0, 0);
        }
    }

    // Epilogue. D-layout: col(n) = lane&15, row(m) = quad*4 + reg.
    #pragma unroll
    for (int i = 0; i < 4; i++) {
        #pragma unroll
        for (int j = 0; j < 4; j++) {
            #pragma unroll
            for (int r = 0; r < 4; r++) {
                int m = m0 + wm*64 + i*16 + quad*4 + r;
                int n = n0 + wn*64 + j*16 + lrow;
                float v = acc[i][j][r];
                if constexpr (MODE == MODE_QK) {
                    // Qt[(h*256+i)*16384 + r*64+d]; h=n>>6,d=n&63,r=m>>8,i=m&255
                    v = (v + bias[n]) * scale;
                    outH[(((long)((n>>6)*256 + (m&255))*256 + (m>>8))<<6) + (n&63)] = (f16)v;
                } else if constexpr (MODE == MODE_V) {
                    // Vt2[((h*256+r)*64+d)*256 + j]; token m: r=m>>8, j=m&255
                    v = v + bias[n];
                    outH[(((long)((n>>6)*256 + (m>>8))*64 + (n&63))<<8) + (m&255)] = (f16)v;
                } else if constexpr (MODE == MODE_SPLIT) {
                    outF[(long)sp*786432 + h*65536 + m*256 + n] = v;
                } else if constexpr (MODE == MODE_CTX) {
                    // CTXh[(r*256+i)*768 + h*64+d]; m=i, n=r*64+d
                    outH[((long)((n>>6)*256 + m))*768 + z*64 + (n&63)] = (f16)v;
                } else { // MODE_OUT
                    outF[(long)m*768 + n] = v + bias[n];
                }
            }
        }
    }
}

// Fused 16-way split-K reduce + shared softmax over j. One block per (h,i) row.
__global__ __launch_bounds__(256) void softmax_k(const float* __restrict__ Sp,
                                                 float* __restrict__ pOut,
                                                 f16* __restrict__ Ph) {
    __shared__ float red[8];
    const int row = blockIdx.x;   // h*256 + i
    const int t = threadIdx.x;    // j
    float v = 0.f;
    #pragma unroll
    for (int s = 0; s < 16; s++)
        v += Sp[(long)s*786432 + (long)row*256 + t];
    float mx = v;
    #pragma unroll
    for (int o = 32; o; o >>= 1) mx = fmaxf(mx, __shfl_xor(mx, o, 64));
    if ((t & 63) == 0) red[t >> 6] = mx;
    __syncthreads();
    mx = fmaxf(fmaxf(red[0], red[1]), fmaxf(red[2], red[3]));
    float e = expf(v - mx);
    float s = e;
    #pragma unroll
    for (int o = 32; o; o >>= 1) s += __shfl_xor(s, o, 64);
    if ((t & 63) == 0) red[4 + (t >> 6)] = s;
    __syncthreads();
    s = red[4] + red[5] + red[6] + red[7];
    float p = e / s;
    pOut[(long)row*256 + t] = p;
    Ph[(long)row*256 + t] = (f16)p;
}

extern "C" void kernel_launch(void* const* d_in, const int* in_sizes, int n_in,
                              void* d_out, int out_size, void* d_ws, size_t ws_size,
                              hipStream_t stream) {
    const float* x  = (const float*)d_in[0];
    const float* Wq = (const float*)d_in[1];
    const float* bq = (const float*)d_in[2];
    const float* Wk = (const float*)d_in[3];
    const float* bk = (const float*)d_in[4];
    const float* Wv = (const float*)d_in[5];
    const float* bv = (const float*)d_in[6];
    const float* Wo = (const float*)d_in[7];
    const float* bo = (const float*)d_in[8];
    float* out   = (float*)d_out;
    float* probs = out + 50331648L;

    char* ws = (char*)d_ws;
    f16*   Xh   = (f16*)(ws + OFF_XH);
    float* Sp   = (float*)(ws + OFF_XH);  // alias: Xh dead after V-proj
    f16*   CTXh = (f16*)(ws + OFF_XH);    // alias: Sp dead after softmax
    f16*   Qt   = (f16*)(ws + OFF_QT);
    f16*   Kt   = (f16*)(ws + OFF_KT);
    f16*   Vt   = (f16*)(ws + OFF_VT);
    f16*   Wqh  = (f16*)(ws + OFF_WQ);
    f16*   Wkh  = (f16*)(ws + OFF_WK);
    f16*   Wvh  = (f16*)(ws + OFF_WV);
    f16*   Woh  = (f16*)(ws + OFF_WO);
    f16*   Ph   = (f16*)(ws + OFF_PH);

    cast_f32_f16<<<24576, 256, 0, stream>>>(x,  Xh,  6291456);
    cast_f32_f16<<<288,   256, 0, stream>>>(Wq, Wqh, 73728);
    cast_f32_f16<<<288,   256, 0, stream>>>(Wk, Wkh, 73728);
    cast_f32_f16<<<288,   256, 0, stream>>>(Wv, Wvh, 73728);
    cast_f32_f16<<<288,   256, 0, stream>>>(Wo, Woh, 73728);

    // projections: M=65536, N=768, K=768
    dim3 g1(6, 512, 1);
    gemm_fast<MODE_QK><<<g1, 256, 0, stream>>>(Xh, Wqh, nullptr, Qt, bq, 1.0f/128.0f, 768, 768, 768);
    gemm_fast<MODE_QK><<<g1, 256, 0, stream>>>(Xh, Wkh, nullptr, Kt, bk, 1.0f,        768, 768, 768);
    gemm_fast<MODE_V ><<<g1, 256, 0, stream>>>(Xh, Wvh, nullptr, Vt, bv, 1.0f,        768, 768, 768);

    // scores: per head M=N=256, K=16384 -> 16-way split-K, fp32 partials in Sp
    gemm_fast<MODE_SPLIT><<<dim3(2, 2, 192), 256, 0, stream>>>(Qt, Kt, Sp, nullptr, nullptr, 1.0f, 16384, 16384, 1024);

    // fused reduce + softmax (3072 rows)
    softmax_k<<<3072, 256, 0, stream>>>(Sp, probs, Ph);

    // context: per head M=256(i), N=16384(r,d), K=256(j)
    gemm_fast<MODE_CTX><<<dim3(128, 2, 12), 256, 0, stream>>>(Ph, Vt, nullptr, CTXh, nullptr, 1.0f, 256, 256, 256);

    // output projection: M=65536, N=768, K=768, fp32 out + bias
    gemm_fast<MODE_OUT><<<g1, 256, 0, stream>>>(CTXh, Woh, out, nullptr, bo, 1.0f, 768, 768, 768);
}